// Round 6
// baseline (249.962 us; speedup 1.0000x reference)
//
#include <hip/hip_runtime.h>
#include <hip/hip_bf16.h>

typedef __bf16 bf16_t;
typedef __attribute__((ext_vector_type(8))) __bf16 bf16x8;
typedef __attribute__((ext_vector_type(4))) __bf16 bf16x4;
typedef __attribute__((ext_vector_type(4))) float f32x4;

#define MFMA16(a, b, c) __builtin_amdgcn_mfma_f32_16x16x32_bf16((a), (b), (c), 0, 0, 0)

__device__ __forceinline__ void gload_lds16(const void* g, void* l) {
    __builtin_amdgcn_global_load_lds(
        (const __attribute__((address_space(1))) void*)g,
        (__attribute__((address_space(3))) void*)l, 16, 0, 0);
}

// ---------------------------------------------------------------------------
// Kernel 1: FUSED QKV projection. One pass over X (HBM read once).
// Tile 128 (M) x 384 (N = Q|K|V), BK = 64, 512 threads (8 waves, 4x2).
// Q pre-scaled by (1/sqrt(128))*log2(e) (softmax runs in base-2 domain).
// V written transposed as [b][h][t].
// ---------------------------------------------------------------------------
__global__ __launch_bounds__(512, 2) void proj_qkv(
    const float* __restrict__ X,
    const float* __restrict__ W0, const float* __restrict__ W1, const float* __restrict__ W2,
    bf16_t* __restrict__ O0, bf16_t* __restrict__ O1, bf16_t* __restrict__ O2)
{
    __shared__ __align__(16) char As[128 * 128];   // 128 m-rows x 64 bf16, 16 KB
    __shared__ __align__(16) char Bs[384 * 128];   // 384 n-rows x 64 bf16, 48 KB

    const int tid = threadIdx.x;
    const int wid = tid >> 6;
    const int lane = tid & 63;
    const int l15 = lane & 15, l4 = lane >> 4;
    const int wr = wid >> 1;          // 0..3 : 32 m-rows each
    const int wc = wid & 1;           // 0..1 : 192 n-cols each
    const int m0 = blockIdx.x * 128;

    const int r0 = tid >> 4;          // 0..31
    const int kq = tid & 15;

    f32x4 acc[2][12] = {};
    float4 xr[4];

    #pragma unroll
    for (int i = 0; i < 4; ++i)
        xr[i] = *(const float4*)(X + (size_t)(m0 + r0 + 32 * i) * 1024 + kq * 4);

    for (int ks = 0; ks < 16; ++ks) {
        const int kb = ks * 64;
        // X slab from prefetch regs -> As
        #pragma unroll
        for (int i = 0; i < 4; ++i) {
            const int r = r0 + 32 * i;
            bf16x4 av; av[0] = (bf16_t)xr[i].x; av[1] = (bf16_t)xr[i].y;
            av[2] = (bf16_t)xr[i].z; av[3] = (bf16_t)xr[i].w;
            *(bf16x4*)(As + r * 128 + ((kq * 8) ^ ((r & 7) << 4))) = av;
        }
        // W slab (L2-hot after first block) -> Bs; rows 0..127 Wq, 128..255 Wk, 256..383 Wv
        #pragma unroll
        for (int i = 0; i < 12; ++i) {
            const int r = r0 + 32 * i;
            const float* Wp = (i < 4) ? W0 : (i < 8 ? W1 : W2);
            const int wrow = r0 + 32 * (i & 3);
            float4 wa = *(const float4*)(Wp + (size_t)wrow * 1024 + kb + kq * 4);
            bf16x4 wv; wv[0] = (bf16_t)wa.x; wv[1] = (bf16_t)wa.y;
            wv[2] = (bf16_t)wa.z; wv[3] = (bf16_t)wa.w;
            *(bf16x4*)(Bs + r * 128 + ((kq * 8) ^ ((r & 7) << 4))) = wv;
        }
        __syncthreads();
        if (ks < 15) {
            #pragma unroll
            for (int i = 0; i < 4; ++i)
                xr[i] = *(const float4*)(X + (size_t)(m0 + r0 + 32 * i) * 1024 + kb + 64 + kq * 4);
        }
        #pragma unroll
        for (int kk = 0; kk < 64; kk += 32) {
            const int kbyte = 2 * kk + 16 * l4;
            bf16x8 af[2], bfr[12];
            #pragma unroll
            for (int mi = 0; mi < 2; ++mi) {
                int r = wr * 32 + mi * 16 + l15;
                af[mi] = *(const bf16x8*)(As + r * 128 + (kbyte ^ ((r & 7) << 4)));
            }
            #pragma unroll
            for (int ni = 0; ni < 12; ++ni) {
                int r = wc * 192 + ni * 16 + l15;
                bfr[ni] = *(const bf16x8*)(Bs + r * 128 + (kbyte ^ ((r & 7) << 4)));
            }
            #pragma unroll
            for (int mi = 0; mi < 2; ++mi)
                #pragma unroll
                for (int ni = 0; ni < 12; ++ni)
                    acc[mi][ni] = MFMA16(af[mi], bfr[ni], acc[mi][ni]);
        }
        __syncthreads();
    }

    // Epilogue. C/D: col = l15, row = l4*4 + r. qs folds 1/sqrt(128)*log2(e).
    const float qs = 0.12751754f;
    #pragma unroll
    for (int mi = 0; mi < 2; ++mi)
        #pragma unroll
        for (int ni = 0; ni < 12; ++ni) {
            const int gcol = 192 * wc + 16 * ni + l15;
            const int sel = gcol >> 7, lc = gcol & 127;
            const int row = m0 + 32 * wr + 16 * mi + 4 * l4;
            if (sel == 0) {
                #pragma unroll
                for (int r = 0; r < 4; ++r)
                    O0[(size_t)(row + r) * 128 + lc] = (bf16_t)(acc[mi][ni][r] * qs);
            } else if (sel == 1) {
                #pragma unroll
                for (int r = 0; r < 4; ++r)
                    O1[(size_t)(row + r) * 128 + lc] = (bf16_t)acc[mi][ni][r];
            } else {
                const int bb = row >> 12, t0 = row & 4095;
                bf16x4 pk;
                #pragma unroll
                for (int r = 0; r < 4; ++r) pk[r] = (bf16_t)acc[mi][ni][r];
                *(bf16x4*)(O2 + ((size_t)bb << 19) + (size_t)lc * 4096 + t0) = pk;
            }
        }
}

// ---------------------------------------------------------------------------
// Kernel 2: causal flash attention, structurally balanced.
// Block = 128 threads (2 waves), handles q-tiles p and 127-p SEQUENTIALLY:
// n(p)+n(127-p) = 33 KVBLK-128 steps for EVERY block -> zero tail, no
// dispatch assumptions. Each wave owns 16 q-rows over the full kv range
// (no merge). S^T = K*Q^T (softmax lane-local per q); base-2 exp.
// K frags from global (L2/L1); V^T double-buffered in LDS (global_load_lds).
// ---------------------------------------------------------------------------
__global__ __launch_bounds__(128) void attn_fwd(
    const bf16_t* __restrict__ Qb, const bf16_t* __restrict__ Kb,
    const bf16_t* __restrict__ Vtg, float* __restrict__ out, int Bn)
{
    // [0,64K): V^T dbuf (2 x 32KB, [128 h][256B kv-row], XOR-swizzled)
    // [64K,72K): P per wave (16 q x 128 kv bf16 = 4KB)
    __shared__ __align__(16) char lds[73728];

    const int tid = threadIdx.x, wid = tid >> 6, lane = tid & 63;
    const int l15 = lane & 15, l4 = lane >> 4;

    const int b = blockIdx.x % Bn;            // batch == XCD -> K/V L2-resident
    const int j = blockIdx.x / Bn;            // 0..63
    const int p1 = j, p2 = 127 - j;
    const int n1 = (p1 >> 2) + 1;             // 128-kv tiles for 32-q tile p
    const int n2 = (p2 >> 2) + 1;
    const int nsteps = n1 + n2;               // == 33 for all blocks

    const size_t base = (size_t)b * 4096 * 128;
    const size_t baseVT = (size_t)b << 19;

    char* Pw = lds + 65536 + wid * 4096;
    const int swzp = (l15 & 7) << 4;

    bf16x8 aq[4];
    float mx, lsum;
    f32x4 o[8];

    auto load_aq = [&](int pc) {
        const bf16_t* qp = Qb + base + (size_t)((pc << 5) + (wid << 4) + l15) * 128 + 8 * l4;
        #pragma unroll
        for (int kf = 0; kf < 4; ++kf) aq[kf] = *(const bf16x8*)(qp + 32 * kf);
    };
    auto reset_state = [&]() {
        mx = -1e30f; lsum = 0.f;
        #pragma unroll
        for (int mf = 0; mf < 8; ++mf) o[mf] = (f32x4){0.f, 0.f, 0.f, 0.f};
    };
    auto store_seg = [&](int pc) {
        const float inv = 1.0f / lsum;
        const int q = (pc << 5) + (wid << 4) + l15;
        float* op = out + ((size_t)b * 4096 + q) * 128 + 4 * l4;
        #pragma unroll
        for (int mf = 0; mf < 8; ++mf) {
            f32x4 r;
            #pragma unroll
            for (int e = 0; e < 4; ++e) r[e] = o[mf][e] * inv;
            *(f32x4*)(op + 16 * mf) = r;
        }
    };
    // Stage V^T tile for global step u into buf (u&1). 32KB, wave covers 64 rows.
    auto stage = [&](int u) {
        const int lt = (u < n1) ? u : u - n1;
        const int kv0 = lt << 7;
        char* dst = lds + (u & 1) * 32768 + wid * 16384;
        const int colb = (lane & 15) << 4;
        #pragma unroll
        for (int i = 0; i < 16; ++i) {
            const int h = wid * 64 + 4 * i + (lane >> 4);
            const bf16_t* src = Vtg + baseVT + (size_t)h * 4096 + kv0
                                + ((colb ^ ((h & 7) << 4)) >> 1);
            gload_lds16(src, dst + i * 1024);
        }
    };

    load_aq(p1);
    reset_state();
    stage(0);
    __syncthreads();

    for (int t = 0; t < nsteps; ++t) {
        if (t == n1) {           // segment switch: finish p1, start p2
            store_seg(p1);
            reset_state();
            load_aq(p2);
        }
        const int pc = (t < n1) ? p1 : p2;
        const int lt = (t < n1) ? t : t - n1;
        const int kv0 = lt << 7;
        const int qw0 = (pc << 5) + (wid << 4);
        const int qg = qw0 + l15;

        if (t + 1 < nsteps) stage(t + 1);     // issue early; lands under compute

        char* Vbuf = lds + (t & 1) * 32768;

        // S^T = K * Q^T : D row = kv (16ni + 4l4 + r), col = q (l15).
        f32x4 sa[8];
        #pragma unroll
        for (int ni = 0; ni < 8; ++ni) sa[ni] = (f32x4){0.f, 0.f, 0.f, 0.f};
        const bf16_t* kp = Kb + base + (size_t)(kv0 + l15) * 128 + 8 * l4;
        #pragma unroll
        for (int ni = 0; ni < 8; ++ni) {
            const bf16_t* kr = kp + (size_t)ni * 2048;
            #pragma unroll
            for (int kf = 0; kf < 4; ++kf) {
                bf16x8 ak = *(const bf16x8*)(kr + 32 * kf);
                sa[ni] = MFMA16(ak, aq[kf], sa[ni]);
            }
        }

        // Causal mask (only near-diagonal tiles).
        if (kv0 + 127 > qw0) {
            #pragma unroll
            for (int ni = 0; ni < 8; ++ni)
                #pragma unroll
                for (int r = 0; r < 4; ++r)
                    if (kv0 + 16 * ni + 4 * l4 + r > qg) sa[ni][r] = -1e30f;
        }

        // Online softmax, base-2 domain (scale*log2e folded into Q).
        float tm = -1e30f;
        #pragma unroll
        for (int ni = 0; ni < 8; ++ni)
            tm = fmaxf(tm, fmaxf(fmaxf(sa[ni][0], sa[ni][1]), fmaxf(sa[ni][2], sa[ni][3])));
        tm = fmaxf(tm, __shfl_xor(tm, 16, 64));
        tm = fmaxf(tm, __shfl_xor(tm, 32, 64));
        const float mnew = fmaxf(mx, tm);
        const float c = exp2f(mx - mnew);
        float ss = 0.f;
        #pragma unroll
        for (int ni = 0; ni < 8; ++ni) {
            #pragma unroll
            for (int r = 0; r < 4; ++r) {
                float pv = exp2f(sa[ni][r] - mnew);
                sa[ni][r] = pv;
                ss += pv;
            }
        }
        ss += __shfl_xor(ss, 16, 64);
        ss += __shfl_xor(ss, 32, 64);
        lsum = lsum * c + ss;
        mx = mnew;
        #pragma unroll
        for (int mf = 0; mf < 8; ++mf) {
            f32x4 tt = o[mf];
            tt[0] *= c; tt[1] *= c; tt[2] *= c; tt[3] *= c;
            o[mf] = tt;
        }

        // P -> per-wave LDS (b64, swizzled).
        #pragma unroll
        for (int ni = 0; ni < 8; ++ni) {
            bf16x4 pv;
            pv[0] = (bf16_t)sa[ni][0]; pv[1] = (bf16_t)sa[ni][1];
            pv[2] = (bf16_t)sa[ni][2]; pv[3] = (bf16_t)sa[ni][3];
            *(bf16x4*)(Pw + l15 * 256 + ((32 * ni + 8 * l4) ^ swzp)) = pv;
        }

        // O^T += V^T * P^T : D row = h (16mf + 4l4 + r), col = q (l15).
        #pragma unroll
        for (int kfp = 0; kfp < 4; ++kfp) {
            const int kb = 64 * kfp + 16 * l4;
            bf16x8 p = *(const bf16x8*)(Pw + l15 * 256 + (kb ^ swzp));
            #pragma unroll
            for (int mf = 0; mf < 8; ++mf) {
                const int h = 16 * mf + l15;
                bf16x8 av = *(const bf16x8*)(Vbuf + h * 256 + (kb ^ ((h & 7) << 4)));
                o[mf] = MFMA16(av, p, o[mf]);
            }
        }

        __syncthreads();   // next-tile stage drained; buf swap safe
    }

    store_seg(p2);
}

extern "C" void kernel_launch(void* const* d_in, const int* in_sizes, int n_in,
                              void* d_out, int out_size, void* d_ws, size_t ws_size,
                              hipStream_t stream) {
    const float* X  = (const float*)d_in[0];
    const float* Wq = (const float*)d_in[1];
    const float* Wk = (const float*)d_in[2];
    const float* Wv = (const float*)d_in[3];
    float* out = (float*)d_out;

    const int M = in_sizes[0] / 1024;      // B*T = 32768
    const int Bn = M / 4096;               // 8

    bf16_t* Qb  = (bf16_t*)d_ws;
    bf16_t* KbP = Qb + (size_t)M * 128;
    bf16_t* VtP = KbP + (size_t)M * 128;   // transposed: [b][128][4096]

    proj_qkv<<<dim3(M / 128), 512, 0, stream>>>(X, Wq, Wk, Wv, Qb, KbP, VtP);
    attn_fwd<<<dim3(64 * Bn), 128, 0, stream>>>(Qb, KbP, VtP, out, Bn);
}

// Round 7
// 144.958 us; speedup vs baseline: 1.7244x; 1.7244x over previous
//
#include <hip/hip_runtime.h>
#include <hip/hip_bf16.h>

typedef __bf16 bf16_t;
typedef __attribute__((ext_vector_type(8))) __bf16 bf16x8;
typedef __attribute__((ext_vector_type(4))) __bf16 bf16x4;
typedef __attribute__((ext_vector_type(4))) float f32x4;

#define MFMA16(a, b, c) __builtin_amdgcn_mfma_f32_16x16x32_bf16((a), (b), (c), 0, 0, 0)

__device__ __forceinline__ void gload_lds16(const void* g, void* l) {
    __builtin_amdgcn_global_load_lds(
        (const __attribute__((address_space(1))) void*)g,
        (__attribute__((address_space(3))) void*)l, 16, 0, 0);
}

// ---------------------------------------------------------------------------
// Kernel 1: QKV projection with X-slab reg-prefetch (best measured: ~37us).
// Out[m][n] = sum_k X[m][k]*W[n][k]; Q pre-scaled by (1/sqrt(128))*log2(e);
// V written transposed as [b][h][t].
// ---------------------------------------------------------------------------
__global__ __launch_bounds__(256, 3) void proj_qkv(
    const float* __restrict__ X,
    const float* __restrict__ W0, const float* __restrict__ W1, const float* __restrict__ W2,
    bf16_t* __restrict__ O0, bf16_t* __restrict__ O1, bf16_t* __restrict__ O2)
{
    __shared__ __align__(16) char As[128 * 128];
    __shared__ __align__(16) char Bs[128 * 128];

    const int tid = threadIdx.x;
    const int wid = tid >> 6;
    const int lane = tid & 63;
    const int l15 = lane & 15, l4 = lane >> 4;
    const int wr = wid >> 1, wc = wid & 1;
    const int m0 = blockIdx.x * 128;

    const float* W = (blockIdx.y == 0) ? W0 : (blockIdx.y == 1 ? W1 : W2);

    const int r0 = tid >> 4;
    const int kq = tid & 15;
    const int swz = ((r0 & 7) << 4);

    f32x4 acc[4][4] = {};
    float4 xr[8];

    #pragma unroll
    for (int i = 0; i < 8; ++i)
        xr[i] = *(const float4*)(X + (size_t)(m0 + r0 + i * 16) * 1024 + kq * 4);

    for (int ks = 0; ks < 16; ++ks) {
        const int kb = ks * 64;
        #pragma unroll
        for (int i = 0; i < 8; ++i) {
            const int r = r0 + i * 16;
            bf16x4 av; av[0] = (bf16_t)xr[i].x; av[1] = (bf16_t)xr[i].y;
            av[2] = (bf16_t)xr[i].z; av[3] = (bf16_t)xr[i].w;
            *(bf16x4*)(As + r * 128 + ((kq * 8) ^ swz)) = av;
        }
        #pragma unroll
        for (int i = 0; i < 8; ++i) {
            const int r = r0 + i * 16;
            float4 wa = *(const float4*)(W + (size_t)r * 1024 + kb + kq * 4);
            bf16x4 wv; wv[0] = (bf16_t)wa.x; wv[1] = (bf16_t)wa.y;
            wv[2] = (bf16_t)wa.z; wv[3] = (bf16_t)wa.w;
            *(bf16x4*)(Bs + r * 128 + ((kq * 8) ^ swz)) = wv;
        }
        __syncthreads();
        if (ks < 15) {
            #pragma unroll
            for (int i = 0; i < 8; ++i)
                xr[i] = *(const float4*)(X + (size_t)(m0 + r0 + i * 16) * 1024 + kb + 64 + kq * 4);
        }
        #pragma unroll
        for (int kk = 0; kk < 64; kk += 32) {
            const int kbyte = 2 * kk + 16 * l4;
            bf16x8 af[4], bfr[4];
            #pragma unroll
            for (int mi = 0; mi < 4; ++mi) {
                int r = wr * 64 + mi * 16 + l15;
                af[mi] = *(const bf16x8*)(As + r * 128 + (kbyte ^ ((r & 7) << 4)));
            }
            #pragma unroll
            for (int ni = 0; ni < 4; ++ni) {
                int r = wc * 64 + ni * 16 + l15;
                bfr[ni] = *(const bf16x8*)(Bs + r * 128 + (kbyte ^ ((r & 7) << 4)));
            }
            #pragma unroll
            for (int mi = 0; mi < 4; ++mi)
                #pragma unroll
                for (int ni = 0; ni < 4; ++ni)
                    acc[mi][ni] = MFMA16(af[mi], bfr[ni], acc[mi][ni]);
        }
        __syncthreads();
    }

    if (blockIdx.y < 2) {
        // Q scale = 1/sqrt(128) * log2(e)  (softmax runs base-2)
        const float sc = (blockIdx.y == 0) ? 0.12751754816f : 1.0f;
        bf16_t* O = (blockIdx.y == 0) ? O0 : O1;
        #pragma unroll
        for (int mi = 0; mi < 4; ++mi)
            #pragma unroll
            for (int ni = 0; ni < 4; ++ni) {
                int row = m0 + wr * 64 + mi * 16 + l4 * 4;
                int col = wc * 64 + ni * 16 + l15;
                #pragma unroll
                for (int r = 0; r < 4; ++r)
                    O[(size_t)(row + r) * 128 + col] = (bf16_t)(acc[mi][ni][r] * sc);
            }
    } else {
        #pragma unroll
        for (int mi = 0; mi < 4; ++mi)
            #pragma unroll
            for (int ni = 0; ni < 4; ++ni) {
                int row0 = m0 + wr * 64 + mi * 16 + l4 * 4;
                int col = wc * 64 + ni * 16 + l15;
                int bb = row0 >> 12, t0 = row0 & 4095;
                bf16x4 pk;
                #pragma unroll
                for (int r = 0; r < 4; ++r) pk[r] = (bf16_t)acc[mi][ni][r];
                *(bf16x4*)(O2 + ((size_t)bb << 19) + (size_t)col * 4096 + t0) = pk;
            }
    }
}

// ---------------------------------------------------------------------------
// Kernel 2: causal flash attention, split-kv pairs (best measured: ~92us).
// 4 waves = 2 pairs; pair A even 64-kv tiles, pair B odd; 32 q-rows/wave,
// S^T = K*Q^T (lane-local softmax stats), end-of-block state merge.
// Staging via global_load_lds(16B), pre-swizzled global addresses.
// Deltas vs best: base-2 softmax (exp2f), setprio around MFMA clusters.
// ---------------------------------------------------------------------------
__global__ __launch_bounds__(256, 2) void attn_fwd(
    const bf16_t* __restrict__ Qb, const bf16_t* __restrict__ Kb,
    const bf16_t* __restrict__ Vtg, float* __restrict__ out, int Bn)
{
    // [0,16K) KsA | [16K,32K) VtA | [32K,48K) KsB | [48K,64K) VtB | [64K,80K) P(4K/wave)
    __shared__ __align__(16) char lds[81920];

    const int tid = threadIdx.x, wid = tid >> 6, lane = tid & 63;
    const int l15 = lane & 15, l4 = lane >> 4;
    const int pair = wid >> 1, qhalf = wid & 1;

    const int L = blockIdx.x;
    const int b = L % Bn;                 // XCD = L%8 = batch -> KV fits per-XCD L2
    const int j = L / Bn;
    const int qt = (j < 32) ? j : 95 - j; // pairing: (j, j+32) -> work sums constant
    const int q0 = qt << 6;
    const int steps = (qt >> 1) + 1;
    const int qw0 = q0 + 32 * qhalf;

    const size_t base = (size_t)b * 4096 * 128;

    bf16x8 aq[2][4];
    #pragma unroll
    for (int qs = 0; qs < 2; ++qs)
        #pragma unroll
        for (int kf = 0; kf < 4; ++kf)
            aq[qs][kf] = *(const bf16x8*)(Qb + base + (size_t)(qw0 + 16 * qs + l15) * 128 + 32 * kf + 8 * l4);

    float mx[2] = {-1e30f, -1e30f}, lsum[2] = {0.f, 0.f};
    f32x4 o[2][8] = {};

    char* Kbuf = lds + pair * 32768;
    char* Vbuf = Kbuf + 16384;
    char* Pw   = lds + 65536 + wid * 4096;
    char* stg  = lds + wid * 16384;       // w0:KsA w1:VtA w2:KsB w3:VtB

    const int sK_r = lane >> 4, sK_c = (lane & 15) << 4;
    const int sV_r = lane >> 3, sV_c = (lane & 7) << 4;

    auto stage = [&](int s) {
        const int t = 2 * s + pair;
        if (t * 64 > q0 + 63) return;     // tile never used by this pair
        const int kv0s = t << 6;
        if ((wid & 1) == 0) {
            // K tile: [64 kv][128 k] bf16, rows 256B, XOR-swizzle via global src
            #pragma unroll
            for (int i = 0; i < 16; ++i) {
                const int row = i * 4 + sK_r;
                const bf16_t* src = Kb + base + (size_t)(kv0s + row) * 128
                                    + ((sK_c ^ ((row & 7) << 4)) >> 1);
                gload_lds16(src, stg + i * 1024);
            }
        } else {
            // V^T tile: [128 h][64 kv] bf16, rows 128B
            #pragma unroll
            for (int i = 0; i < 16; ++i) {
                const int h = i * 8 + sV_r;
                const bf16_t* src = Vtg + base + (size_t)h * 4096 + kv0s
                                    + ((sV_c ^ ((h & 7) << 4)) >> 1);
                gload_lds16(src, stg + i * 1024);
            }
        }
    };

    stage(0);
    __syncthreads();

    for (int s = 0; s < steps; ++s) {
        const int tw = 2 * s + pair;
        const int kv0 = tw << 6;
        if (kv0 <= qw0 + 31) {
            // S^T = K * Q^T : D row = kv-in-tile (4*l4+r), col = q (l15)
            f32x4 sa[2][4];
            #pragma unroll
            for (int qs = 0; qs < 2; ++qs)
                #pragma unroll
                for (int ni = 0; ni < 4; ++ni) sa[qs][ni] = (f32x4){0.f, 0.f, 0.f, 0.f};
            __builtin_amdgcn_s_setprio(1);
            #pragma unroll
            for (int kf = 0; kf < 4; ++kf) {
                const int kb = 64 * kf + 16 * l4;
                #pragma unroll
                for (int ni = 0; ni < 4; ++ni) {
                    const int krow = 16 * ni + l15;
                    bf16x8 ak = *(const bf16x8*)(Kbuf + krow * 256 + (kb ^ ((krow & 7) << 4)));
                    sa[0][ni] = MFMA16(ak, aq[0][kf], sa[0][ni]);
                    sa[1][ni] = MFMA16(ak, aq[1][kf], sa[1][ni]);
                }
            }
            __builtin_amdgcn_s_setprio(0);
            #pragma unroll
            for (int qs = 0; qs < 2; ++qs) {
                const int qg = qw0 + 16 * qs + l15;
                if (kv0 + 63 > qw0 + 16 * qs) {   // only near-diagonal tiles mask
                    #pragma unroll
                    for (int ni = 0; ni < 4; ++ni)
                        #pragma unroll
                        for (int r = 0; r < 4; ++r)
                            if (kv0 + 16 * ni + 4 * l4 + r > qg) sa[qs][ni][r] = -1e30f;
                }
                float tm = sa[qs][0][0];
                #pragma unroll
                for (int ni = 0; ni < 4; ++ni)
                    #pragma unroll
                    for (int r = 0; r < 4; ++r) tm = fmaxf(tm, sa[qs][ni][r]);
                tm = fmaxf(tm, __shfl_xor(tm, 16, 64));
                tm = fmaxf(tm, __shfl_xor(tm, 32, 64));
                const float mnew = fmaxf(mx[qs], tm);
                const float c = exp2f(mx[qs] - mnew);
                float ssum = 0.f;
                #pragma unroll
                for (int ni = 0; ni < 4; ++ni)
                    #pragma unroll
                    for (int r = 0; r < 4; ++r) {
                        float pv = exp2f(sa[qs][ni][r] - mnew);
                        sa[qs][ni][r] = pv;
                        ssum += pv;
                    }
                ssum += __shfl_xor(ssum, 16, 64);
                ssum += __shfl_xor(ssum, 32, 64);
                lsum[qs] = lsum[qs] * c + ssum;
                mx[qs] = mnew;
                #pragma unroll
                for (int mf = 0; mf < 8; ++mf) {
                    f32x4 t = o[qs][mf];
                    t[0] *= c; t[1] *= c; t[2] *= c; t[3] *= c;
                    o[qs][mf] = t;
                }
                // P[q][kv] b64 packed writes, swizzled
                const int rowb = (16 * qs + l15) * 128;
                const int swz = (l15 & 7) << 4;
                #pragma unroll
                for (int ni = 0; ni < 4; ++ni) {
                    bf16x4 pv;
                    pv[0] = (bf16_t)sa[qs][ni][0]; pv[1] = (bf16_t)sa[qs][ni][1];
                    pv[2] = (bf16_t)sa[qs][ni][2]; pv[3] = (bf16_t)sa[qs][ni][3];
                    *(bf16x4*)(Pw + rowb + ((32 * ni + 8 * l4) ^ swz)) = pv;
                }
            }
            // O^T += V^T * P^T : D row = h (4*l4+r in tile mf), col = q (l15)
            const int swzp = (l15 & 7) << 4;
            __builtin_amdgcn_s_setprio(1);
            #pragma unroll
            for (int kfp = 0; kfp < 2; ++kfp) {
                const int kb = 64 * kfp + 16 * l4;
                bf16x8 p0 = *(const bf16x8*)(Pw + l15 * 128 + (kb ^ swzp));
                bf16x8 p1 = *(const bf16x8*)(Pw + (16 + l15) * 128 + (kb ^ swzp));
                #pragma unroll
                for (int mf = 0; mf < 8; ++mf) {
                    const int h = 16 * mf + l15;
                    bf16x8 av = *(const bf16x8*)(Vbuf + h * 128 + (kb ^ ((h & 7) << 4)));
                    o[0][mf] = MFMA16(av, p0, o[0][mf]);
                    o[1][mf] = MFMA16(av, p1, o[1][mf]);
                }
            }
            __builtin_amdgcn_s_setprio(0);
        }
        if (s + 1 < steps) {
            __syncthreads();   // all reads of current tiles done
            stage(s + 1);
            __syncthreads();   // staged data visible (vmcnt drained at barrier)
        }
    }

    // Merge pair B's online state into pair A's, then store.
    __syncthreads();
    if (wid >= 2) {
        char* dst = lds + (wid - 2) * 16384;
        #pragma unroll
        for (int qs = 0; qs < 2; ++qs)
            #pragma unroll
            for (int mf = 0; mf < 8; ++mf)
                *(f32x4*)(dst + (qs * 8 + mf) * 1024 + lane * 16) = o[qs][mf];
        f32x4 st; st[0] = mx[0]; st[1] = lsum[0]; st[2] = mx[1]; st[3] = lsum[1];
        *(f32x4*)(lds + 32768 + (wid - 2) * 1024 + lane * 16) = st;
    }
    __syncthreads();
    if (wid < 2) {
        char* srcO = lds + wid * 16384;
        f32x4 st = *(const f32x4*)(lds + 32768 + wid * 1024 + lane * 16);
        #pragma unroll
        for (int qs = 0; qs < 2; ++qs) {
            const float mB = st[2 * qs], lB = st[2 * qs + 1];
            const float mm = fmaxf(mx[qs], mB);
            const float a = exp2f(mx[qs] - mm), bb = exp2f(mB - mm);
            const float linv = 1.f / (lsum[qs] * a + lB * bb);
            const int qg = qw0 + 16 * qs + l15;
            float* op = out + ((size_t)b * 4096 + qg) * 128;
            #pragma unroll
            for (int mf = 0; mf < 8; ++mf) {
                f32x4 ob = *(const f32x4*)(srcO + (qs * 8 + mf) * 1024 + lane * 16);
                f32x4 r;
                #pragma unroll
                for (int e = 0; e < 4; ++e) r[e] = (o[qs][mf][e] * a + ob[e] * bb) * linv;
                *(f32x4*)(op + 16 * mf + 4 * l4) = r;
            }
        }
    }
}

extern "C" void kernel_launch(void* const* d_in, const int* in_sizes, int n_in,
                              void* d_out, int out_size, void* d_ws, size_t ws_size,
                              hipStream_t stream) {
    const float* X  = (const float*)d_in[0];
    const float* Wq = (const float*)d_in[1];
    const float* Wk = (const float*)d_in[2];
    const float* Wv = (const float*)d_in[3];
    float* out = (float*)d_out;

    const int M = in_sizes[0] / 1024;      // B*T = 32768
    const int Bn = M / 4096;               // 8

    bf16_t* Qb  = (bf16_t*)d_ws;
    bf16_t* KbP = Qb + (size_t)M * 128;
    bf16_t* VtP = KbP + (size_t)M * 128;   // transposed: [b][128][4096]

    proj_qkv<<<dim3(M / 128, 3), 256, 0, stream>>>(X, Wq, Wk, Wv, Qb, KbP, VtP);
    attn_fwd<<<dim3(64 * Bn), 256, 0, stream>>>(Qb, KbP, VtP, out, Bn);
}

// Round 8
// 139.682 us; speedup vs baseline: 1.7895x; 1.0378x over previous
//
#include <hip/hip_runtime.h>
#include <hip/hip_bf16.h>

typedef __bf16 bf16_t;
typedef __attribute__((ext_vector_type(8))) __bf16 bf16x8;
typedef __attribute__((ext_vector_type(4))) __bf16 bf16x4;
typedef __attribute__((ext_vector_type(4))) float f32x4;

#define MFMA16(a, b, c) __builtin_amdgcn_mfma_f32_16x16x32_bf16((a), (b), (c), 0, 0, 0)

__device__ __forceinline__ void gload_lds16(const void* g, void* l) {
    __builtin_amdgcn_global_load_lds(
        (const __attribute__((address_space(1))) void*)g,
        (__attribute__((address_space(3))) void*)l, 16, 0, 0);
}

// ---------------------------------------------------------------------------
// Kernel 1: QKV projection (r7, unchanged). Q pre-scaled by (1/sqrt(128))*log2e;
// V written transposed as [b][h][t].
// ---------------------------------------------------------------------------
__global__ __launch_bounds__(256, 3) void proj_qkv(
    const float* __restrict__ X,
    const float* __restrict__ W0, const float* __restrict__ W1, const float* __restrict__ W2,
    bf16_t* __restrict__ O0, bf16_t* __restrict__ O1, bf16_t* __restrict__ O2)
{
    __shared__ __align__(16) char As[128 * 128];
    __shared__ __align__(16) char Bs[128 * 128];

    const int tid = threadIdx.x;
    const int wid = tid >> 6;
    const int lane = tid & 63;
    const int l15 = lane & 15, l4 = lane >> 4;
    const int wr = wid >> 1, wc = wid & 1;
    const int m0 = blockIdx.x * 128;

    const float* W = (blockIdx.y == 0) ? W0 : (blockIdx.y == 1 ? W1 : W2);

    const int r0 = tid >> 4;
    const int kq = tid & 15;
    const int swz = ((r0 & 7) << 4);

    f32x4 acc[4][4] = {};
    float4 xr[8];

    #pragma unroll
    for (int i = 0; i < 8; ++i)
        xr[i] = *(const float4*)(X + (size_t)(m0 + r0 + i * 16) * 1024 + kq * 4);

    for (int ks = 0; ks < 16; ++ks) {
        const int kb = ks * 64;
        #pragma unroll
        for (int i = 0; i < 8; ++i) {
            const int r = r0 + i * 16;
            bf16x4 av; av[0] = (bf16_t)xr[i].x; av[1] = (bf16_t)xr[i].y;
            av[2] = (bf16_t)xr[i].z; av[3] = (bf16_t)xr[i].w;
            *(bf16x4*)(As + r * 128 + ((kq * 8) ^ swz)) = av;
        }
        #pragma unroll
        for (int i = 0; i < 8; ++i) {
            const int r = r0 + i * 16;
            float4 wa = *(const float4*)(W + (size_t)r * 1024 + kb + kq * 4);
            bf16x4 wv; wv[0] = (bf16_t)wa.x; wv[1] = (bf16_t)wa.y;
            wv[2] = (bf16_t)wa.z; wv[3] = (bf16_t)wa.w;
            *(bf16x4*)(Bs + r * 128 + ((kq * 8) ^ swz)) = wv;
        }
        __syncthreads();
        if (ks < 15) {
            #pragma unroll
            for (int i = 0; i < 8; ++i)
                xr[i] = *(const float4*)(X + (size_t)(m0 + r0 + i * 16) * 1024 + kb + 64 + kq * 4);
        }
        #pragma unroll
        for (int kk = 0; kk < 64; kk += 32) {
            const int kbyte = 2 * kk + 16 * l4;
            bf16x8 af[4], bfr[4];
            #pragma unroll
            for (int mi = 0; mi < 4; ++mi) {
                int r = wr * 64 + mi * 16 + l15;
                af[mi] = *(const bf16x8*)(As + r * 128 + (kbyte ^ ((r & 7) << 4)));
            }
            #pragma unroll
            for (int ni = 0; ni < 4; ++ni) {
                int r = wc * 64 + ni * 16 + l15;
                bfr[ni] = *(const bf16x8*)(Bs + r * 128 + (kbyte ^ ((r & 7) << 4)));
            }
            #pragma unroll
            for (int mi = 0; mi < 4; ++mi)
                #pragma unroll
                for (int ni = 0; ni < 4; ++ni)
                    acc[mi][ni] = MFMA16(af[mi], bfr[ni], acc[mi][ni]);
        }
        __syncthreads();
    }

    if (blockIdx.y < 2) {
        const float sc = (blockIdx.y == 0) ? 0.12751754816f : 1.0f;  // 1/sqrt(128)*log2e
        bf16_t* O = (blockIdx.y == 0) ? O0 : O1;
        #pragma unroll
        for (int mi = 0; mi < 4; ++mi)
            #pragma unroll
            for (int ni = 0; ni < 4; ++ni) {
                int row = m0 + wr * 64 + mi * 16 + l4 * 4;
                int col = wc * 64 + ni * 16 + l15;
                #pragma unroll
                for (int r = 0; r < 4; ++r)
                    O[(size_t)(row + r) * 128 + col] = (bf16_t)(acc[mi][ni][r] * sc);
            }
    } else {
        #pragma unroll
        for (int mi = 0; mi < 4; ++mi)
            #pragma unroll
            for (int ni = 0; ni < 4; ++ni) {
                int row0 = m0 + wr * 64 + mi * 16 + l4 * 4;
                int col = wc * 64 + ni * 16 + l15;
                int bb = row0 >> 12, t0 = row0 & 4095;
                bf16x4 pk;
                #pragma unroll
                for (int r = 0; r < 4; ++r) pk[r] = (bf16_t)acc[mi][ni][r];
                *(bf16x4*)(O2 + ((size_t)bb << 19) + (size_t)col * 4096 + t0) = pk;
            }
    }
}

// ---------------------------------------------------------------------------
// Kernel 2: causal flash attention — equal-length blocks, barrier-free loop.
// 512 blocks x 4 waves. Block processes 32q atoms p=j then p=127-j (129
// 32-kv tiles total, identical for ALL blocks; 2 blocks/CU all-resident).
// Within an atom: waves kv-split mod 4, fully autonomous: own V tile staged
// via global_load_lds (8KB dbuf, counted-vmcnt sync, NO barriers), K frags
// read direct from L2 (batch==XCD), K prefetched under softmax+PV.
// Per-atom 4-state merge via LDS (3 barriers per atom).
// ---------------------------------------------------------------------------
__global__ __launch_bounds__(256, 2) void attn_fwd(
    const bf16_t* __restrict__ Qb, const bf16_t* __restrict__ Kb,
    const bf16_t* __restrict__ Vtg, float* __restrict__ out, int Bn)
{
    // [0,64K): per-wave V dbuf (16KB each: 2 x 8KB [128h][64B kv-row]).
    //          merge phase reuses [0,64K) as 4 x 16KB O-dump.
    // [64K,72K): per-wave P (2KB: [32q][64B kv-row]); merge stats overlay.
    __shared__ __align__(16) char lds[73728];

    const int tid = threadIdx.x, wid = tid >> 6, lane = tid & 63;
    const int l15 = lane & 15, l4 = lane >> 4;

    const int blk = blockIdx.x;
    const int b = blk % Bn;              // batch == XCD -> K/V L2-resident
    const int j = blk / Bn;              // 0..63

    const size_t base = (size_t)b * 4096 * 128;
    const size_t baseVT = (size_t)b << 19;

    char* Vw = lds + wid * 16384;
    char* Pw = lds + 65536 + wid * 2048;

    const int sh = lane >> 2;            // staging: row within 16-row chunk
    const int skb = (lane & 3) * 8;      // staging: kv elem offset

    for (int seg = 0; seg < 2; ++seg) {
        const int p = seg ? (127 - j) : j;     // 32q atom index
        const int q0 = p << 5;
        const int nt = (p >= wid) ? ((p - wid) >> 2) + 1 : 0;  // my tiles: lt = wid+4i

        // Q fragments (B-operand): col q = q0+16qs+l15, k = 32kf+8l4+e.
        bf16x8 aq[2][4];
        #pragma unroll
        for (int qs = 0; qs < 2; ++qs)
            #pragma unroll
            for (int kf = 0; kf < 4; ++kf)
                aq[qs][kf] = *(const bf16x8*)(Qb + base
                    + (size_t)(q0 + 16 * qs + l15) * 128 + 32 * kf + 8 * l4);

        float mx[2] = {-1e30f, -1e30f}, lsum[2] = {0.f, 0.f};
        f32x4 o[2][8] = {};
        bf16x8 kreg[2][4];

        auto stageV = [&](int i) {
            const int kv0 = (wid + 4 * i) << 5;
            char* dst = Vw + (i & 1) * 8192;
            #pragma unroll
            for (int c = 0; c < 8; ++c) {
                const bf16_t* src = Vtg + baseVT + (size_t)(16 * c + sh) * 4096 + kv0 + skb;
                gload_lds16(src, dst + c * 1024);
            }
        };
        auto loadK = [&](int i) {
            const int kv0 = (wid + 4 * i) << 5;
            const bf16_t* kp = Kb + base + (size_t)(kv0 + l15) * 128 + 8 * l4;
            #pragma unroll
            for (int ni = 0; ni < 2; ++ni)
                #pragma unroll
                for (int kf = 0; kf < 4; ++kf)
                    kreg[ni][kf] = *(const bf16x8*)(kp + (size_t)ni * 2048 + kf * 32);
        };

        if (nt > 0) { loadK(0); stageV(0); }

        for (int i = 0; i < nt; ++i) {
            const int lt = wid + 4 * i;
            const int kv0 = lt << 5;

            // S^T = K * Q^T : D row = kv (16ni+4l4+r), col = q (l15).
            f32x4 sa[2][2];
            #pragma unroll
            for (int qs = 0; qs < 2; ++qs)
                #pragma unroll
                for (int ni = 0; ni < 2; ++ni) sa[qs][ni] = (f32x4){0.f, 0.f, 0.f, 0.f};
            __builtin_amdgcn_s_setprio(1);
            #pragma unroll
            for (int kf = 0; kf < 4; ++kf)
                #pragma unroll
                for (int ni = 0; ni < 2; ++ni) {
                    sa[0][ni] = MFMA16(kreg[ni][kf], aq[0][kf], sa[0][ni]);
                    sa[1][ni] = MFMA16(kreg[ni][kf], aq[1][kf], sa[1][ni]);
                }
            __builtin_amdgcn_s_setprio(0);

            if (i + 1 < nt) loadK(i + 1);   // prefetch: hidden under softmax+PV

            if (lt == p) {                  // only the diagonal tile masks
                #pragma unroll
                for (int qs = 0; qs < 2; ++qs) {
                    const int qg = q0 + 16 * qs + l15;
                    #pragma unroll
                    for (int ni = 0; ni < 2; ++ni)
                        #pragma unroll
                        for (int r = 0; r < 4; ++r)
                            if (kv0 + 16 * ni + 4 * l4 + r > qg) sa[qs][ni][r] = -1e30f;
                }
            }

            // Online softmax (base-2; stats lane-local per q, shfl over l4 bits).
            #pragma unroll
            for (int qs = 0; qs < 2; ++qs) {
                float tm = sa[qs][0][0];
                #pragma unroll
                for (int ni = 0; ni < 2; ++ni)
                    #pragma unroll
                    for (int r = 0; r < 4; ++r) tm = fmaxf(tm, sa[qs][ni][r]);
                tm = fmaxf(tm, __shfl_xor(tm, 16, 64));
                tm = fmaxf(tm, __shfl_xor(tm, 32, 64));
                if (__any(tm > mx[qs])) {        // exact defer: skip no-op rescale
                    const float mnew = fmaxf(mx[qs], tm);
                    const float c = exp2f(mx[qs] - mnew);
                    lsum[qs] *= c;
                    #pragma unroll
                    for (int mf = 0; mf < 8; ++mf) {
                        f32x4 t = o[qs][mf];
                        t[0] *= c; t[1] *= c; t[2] *= c; t[3] *= c;
                        o[qs][mf] = t;
                    }
                    mx[qs] = mnew;
                }
                float ss = 0.f;
                #pragma unroll
                for (int ni = 0; ni < 2; ++ni)
                    #pragma unroll
                    for (int r = 0; r < 4; ++r) {
                        float pv = exp2f(sa[qs][ni][r] - mx[qs]);
                        sa[qs][ni][r] = pv;
                        ss += pv;
                    }
                ss += __shfl_xor(ss, 16, 64);
                ss += __shfl_xor(ss, 32, 64);
                lsum[qs] += ss;
                // P write: row q (64B rows), b64 packed.
                #pragma unroll
                for (int ni = 0; ni < 2; ++ni) {
                    bf16x4 pv;
                    pv[0] = (bf16_t)sa[qs][ni][0]; pv[1] = (bf16_t)sa[qs][ni][1];
                    pv[2] = (bf16_t)sa[qs][ni][2]; pv[3] = (bf16_t)sa[qs][ni][3];
                    *(bf16x4*)(Pw + (16 * qs + l15) * 64 + 32 * ni + 8 * l4) = pv;
                }
            }

            // V(i) readiness: keep 8 newest (K prefetch), drain stageV(i).
            __builtin_amdgcn_sched_barrier(0);
            asm volatile("s_waitcnt vmcnt(8)" ::: "memory");
            __builtin_amdgcn_sched_barrier(0);

            // O^T += V^T * P^T : D row = h (16mf+4l4+r), col = q (l15).
            char* Vbuf = Vw + (i & 1) * 8192;
            bf16x8 pa0 = *(const bf16x8*)(Pw + l15 * 64 + 16 * l4);
            bf16x8 pa1 = *(const bf16x8*)(Pw + (16 + l15) * 64 + 16 * l4);
            __builtin_amdgcn_s_setprio(1);
            #pragma unroll
            for (int mf = 0; mf < 8; ++mf) {
                bf16x8 av = *(const bf16x8*)(Vbuf + (16 * mf + l15) * 64 + 16 * l4);
                o[0][mf] = MFMA16(av, pa0, o[0][mf]);
                o[1][mf] = MFMA16(av, pa1, o[1][mf]);
            }
            __builtin_amdgcn_s_setprio(0);

            if (i + 1 < nt) stageV(i + 1);  // lands across the loop-back edge
        }

        // ---- per-atom merge of the 4 kv-split states ----
        asm volatile("s_waitcnt vmcnt(0)" ::: "memory");
        __syncthreads();
        #pragma unroll
        for (int qs = 0; qs < 2; ++qs)
            #pragma unroll
            for (int mf = 0; mf < 8; ++mf)
                *(f32x4*)(lds + wid * 16384 + (qs * 8 + mf) * 1024 + lane * 16) = o[qs][mf];
        if (l4 == 0) {
            #pragma unroll
            for (int qs = 0; qs < 2; ++qs)
                *(float2*)(lds + 65536 + wid * 256 + (qs * 16 + l15) * 8)
                    = make_float2(mx[qs], lsum[qs]);
        }
        __syncthreads();
        #pragma unroll
        for (int qs = 0; qs < 2; ++qs) {
            float mw[4], lw[4];
            #pragma unroll
            for (int w = 0; w < 4; ++w) {
                float2 st = *(const float2*)(lds + 65536 + w * 256 + (qs * 16 + l15) * 8);
                mw[w] = st.x; lw[w] = st.y;
            }
            const float M = fmaxf(fmaxf(mw[0], mw[1]), fmaxf(mw[2], mw[3]));
            float cw[4], L = 0.f;
            #pragma unroll
            for (int w = 0; w < 4; ++w) { cw[w] = exp2f(mw[w] - M); L += lw[w] * cw[w]; }
            const float inv = 1.f / L;
            #pragma unroll
            for (int mm = 0; mm < 2; ++mm) {
                const int mf = 2 * wid + mm;    // this wave's h-slice
                f32x4 acc = (f32x4){0.f, 0.f, 0.f, 0.f};
                #pragma unroll
                for (int w = 0; w < 4; ++w) {
                    f32x4 v = *(const f32x4*)(lds + w * 16384 + (qs * 8 + mf) * 1024 + lane * 16);
                    #pragma unroll
                    for (int e = 0; e < 4; ++e) acc[e] += v[e] * cw[w];
                }
                #pragma unroll
                for (int e = 0; e < 4; ++e) acc[e] *= inv;
                float* op = out + ((size_t)b * 4096 + q0 + 16 * qs + l15) * 128 + 16 * mf + 4 * l4;
                *(f32x4*)op = acc;
            }
        }
        __syncthreads();   // V region safe to re-stage for the next atom
    }
}

extern "C" void kernel_launch(void* const* d_in, const int* in_sizes, int n_in,
                              void* d_out, int out_size, void* d_ws, size_t ws_size,
                              hipStream_t stream) {
    const float* X  = (const float*)d_in[0];
    const float* Wq = (const float*)d_in[1];
    const float* Wk = (const float*)d_in[2];
    const float* Wv = (const float*)d_in[3];
    float* out = (float*)d_out;

    const int M = in_sizes[0] / 1024;      // B*T = 32768
    const int Bn = M / 4096;               // 8

    bf16_t* Qb  = (bf16_t*)d_ws;
    bf16_t* KbP = Qb + (size_t)M * 128;
    bf16_t* VtP = KbP + (size_t)M * 128;   // transposed: [b][128][4096]

    proj_qkv<<<dim3(M / 128, 3), 256, 0, stream>>>(X, Wq, Wk, Wv, Qb, KbP, VtP);
    attn_fwd<<<dim3(64 * Bn), 256, 0, stream>>>(Qb, KbP, VtP, out, Bn);
}